// Round 6
// baseline (318.101 us; speedup 1.0000x reference)
//
#include <hip/hip_runtime.h>
#include <math.h>

#define BB 2
#define DD 16
#define HH 64
#define WW 64
#define WF 33   // WW/2+1
#define CC 256

typedef __attribute__((ext_vector_type(8))) short bf16x8;
typedef __attribute__((ext_vector_type(4))) float f32x4;
typedef __attribute__((ext_vector_type(4))) unsigned int u32x4;

__device__ __forceinline__ unsigned short f2bf(float f) {
    unsigned u = __builtin_bit_cast(unsigned int, f);
    u += 0x7fffu + ((u >> 16) & 1u);   // round-to-nearest-even
    return (unsigned short)(u >> 16);
}

__device__ __forceinline__ bf16x8 bneg(bf16x8 a) {
    u32x4 u = __builtin_bit_cast(u32x4, a);
    u = u ^ 0x80008000u;               // flip both packed bf16 signs
    return __builtin_bit_cast(bf16x8, u);
}

__device__ __forceinline__ float2 cmul(float2 a, float2 b) {
    return make_float2(a.x * b.x - a.y * b.y, a.x * b.y + a.y * b.x);
}

// Fully-unrolled in-register radix-2 DIT complex FFT. INV=true => e^{+i}, unnormalized.
template <int N, bool INV>
__device__ __forceinline__ void cfft(float2* v) {
    constexpr int L = (N == 64) ? 6 : (N == 32) ? 5 : (N == 16) ? 4 : 0;
    static_assert(L > 0, "unsupported N");
#pragma unroll
    for (int i = 0; i < N; ++i) {
        int j = 0;
#pragma unroll
        for (int bpos = 0; bpos < L; ++bpos) j |= ((i >> bpos) & 1) << (L - 1 - bpos);
        if (j > i) { float2 t = v[i]; v[i] = v[j]; v[j] = t; }
    }
#pragma unroll
    for (int s = 1; s <= L; ++s) {
        const int m = 1 << s;
#pragma unroll
        for (int k = 0; k < N; k += m) {
#pragma unroll
            for (int j = 0; j < m / 2; ++j) {
                float ang = (INV ? 2.0f : -2.0f) * 3.14159265358979323846f * (float)j / (float)m;
                float ss, cc;
                __sincosf(ang, &ss, &cc);
                float2 w = make_float2(cc, ss);
                float2 u = v[k + j];
                float2 t = cmul(w, v[k + j + m / 2]);
                v[k + j]         = make_float2(u.x + t.x, u.y + t.y);
                v[k + j + m / 2] = make_float2(u.x - t.x, u.y - t.y);
            }
        }
    }
}

// Kernel A: rfft along W via packed complex FFT-32 + Hermitian unpack.
// grid (H, D, B), 256 threads = channels.
__global__ __launch_bounds__(256) void kA(const float* __restrict__ x, float2* __restrict__ spec) {
    const int h = blockIdx.x, d = blockIdx.y, b = blockIdx.z, c = threadIdx.x;
    const float* px = x + (((size_t)(b * DD + d) * HH + h) * WW) * CC + c;
    float2 z[32];
#pragma unroll
    for (int m = 0; m < 32; ++m)
        z[m] = make_float2(px[(size_t)(2 * m) * CC], px[(size_t)(2 * m + 1) * CC]);
    cfft<32, false>(z);
    float2* ps = spec + (((size_t)(b * DD + d) * HH + h) * WF) * CC + c;
    const float s = 1.0f / 256.0f;
    // k=0 / k=32 (Nyquist): X0 = ReZ0 + ImZ0, X32 = ReZ0 - ImZ0 (both real)
    ps[0]                 = make_float2((z[0].x + z[0].y) * s, 0.0f);
    ps[(size_t)32 * CC]   = make_float2((z[0].x - z[0].y) * s, 0.0f);
#pragma unroll
    for (int k = 1; k < 32; ++k) {
        float2 a = z[k], bb = z[32 - k];
        float2 E = make_float2(0.5f * (a.x + bb.x), 0.5f * (a.y - bb.y));
        float2 P = make_float2(0.5f * (a.x - bb.x), 0.5f * (a.y + bb.y));
        float th = 3.14159265358979323846f * (float)k / 32.0f;
        float ss, cc;
        __sincosf(th, &ss, &cc);
        float2 u = make_float2(-ss, -cc);        // e^{-i th} * (-i)
        float2 X = make_float2(E.x + u.x * P.x - u.y * P.y,
                               E.y + u.x * P.y + u.y * P.x);
        ps[(size_t)k * CC] = make_float2(X.x * s, X.y * s);
    }
}

// Kernel B/D: complex FFT along H, in-place. grid (WF, D, B).
template <bool INV>
__global__ __launch_bounds__(256) void kH(float2* __restrict__ spec) {
    const int wf = blockIdx.x, d = blockIdx.y, b = blockIdx.z, c = threadIdx.x;
    float2* ps = spec + (((size_t)(b * DD + d) * HH) * WF + wf) * CC + c;
    const size_t sh = (size_t)WF * CC;
    float2 v[HH];
#pragma unroll
    for (int h = 0; h < HH; ++h) v[h] = ps[(size_t)h * sh];
    cfft<64, INV>(v);
#pragma unroll
    for (int h = 0; h < HH; ++h) ps[(size_t)h * sh] = v[h];
}

__device__ __forceinline__ float softshrink(float v) {
    return (v > 0.01f) ? v - 0.01f : ((v < -0.01f) ? v + 0.01f : 0.0f);
}

// Kernel C: FFT-D + MFMA block-MLP + iFFT-D, in-place. grid (WF, H, B), 256 thr = 4 waves.
__global__ __launch_bounds__(256) void kC(float2* __restrict__ spec,
                                          const float* __restrict__ w1, const float* __restrict__ b1,
                                          const float* __restrict__ w2, const float* __restrict__ b2) {
    const int wf = blockIdx.x, h = blockIdx.y, b = blockIdx.z;
    const int c = threadIdx.x;
    const int wv = c >> 6, lane = c & 63;
    const int lrow = lane & 15, lgrp = lane >> 4;

    __shared__ __align__(16) unsigned char smem[32768];

    float2* ps = spec + (((size_t)b * DD * HH + h) * WF + wf) * CC + c;
    const size_t sd = (size_t)HH * WF * CC;

    float b1r_[2][2], b1i_[2][2], b2r_[2][2], b2i_[2][2];
#pragma unroll
    for (int nb = 0; nb < 2; ++nb) {
        const int n = 2 * wv + nb;
#pragma unroll
        for (int t = 0; t < 2; ++t) {
            const int ob = n * 32 + t * 16 + lrow;
            b1r_[nb][t] = b1[ob];  b1i_[nb][t] = b1[256 + ob];
            b2r_[nb][t] = b2[ob];  b2i_[nb][t] = b2[256 + ob];
        }
    }

    bf16x8 Wr[2][2], Wi[2][2];
#pragma unroll
    for (int nb = 0; nb < 2; ++nb) {
        const int n = 2 * wv + nb;
#pragma unroll
        for (int t = 0; t < 2; ++t) {
            const int col = t * 16 + lrow;
#pragma unroll
            for (int j = 0; j < 8; ++j) {
                const int k = lgrp * 8 + j;
                Wr[nb][t][j] = (short)f2bf(w1[n * 1024 + k * 32 + col]);
                Wi[nb][t][j] = (short)f2bf(w1[8192 + n * 1024 + k * 32 + col]);
            }
        }
    }

    float2 v[DD];
#pragma unroll
    for (int d = 0; d < DD; ++d) v[d] = ps[(size_t)d * sd];
    cfft<16, false>(v);

    {
        const int n = c >> 5, in = c & 31;
        unsigned short* Ar = (unsigned short*)smem;
#pragma unroll
        for (int d = 0; d < DD; ++d) {
            Ar[n * 512 + d * 32 + in]        = f2bf(v[d].x);
            Ar[4096 + n * 512 + d * 32 + in] = f2bf(v[d].y);
        }
    }
    __syncthreads();

    const f32x4 zero = {0.f, 0.f, 0.f, 0.f};

#pragma unroll
    for (int nb = 0; nb < 2; ++nb) {
        const int n = 2 * wv + nb;
        const int abase = n * 1024 + lrow * 64 + lgrp * 16;
        bf16x8 xr  = *(const bf16x8*)(smem + abase);
        bf16x8 xi  = *(const bf16x8*)(smem + 8192 + abase);
        bf16x8 nxi = bneg(xi);
        unsigned short* H = (unsigned short*)(smem + 16384);
#pragma unroll
        for (int t = 0; t < 2; ++t) {
            f32x4 rr = __builtin_amdgcn_mfma_f32_16x16x32_bf16(xr, Wr[nb][t], zero, 0, 0, 0);
            rr = __builtin_amdgcn_mfma_f32_16x16x32_bf16(nxi, Wi[nb][t], rr, 0, 0, 0);
            f32x4 ii = __builtin_amdgcn_mfma_f32_16x16x32_bf16(xi, Wr[nb][t], zero, 0, 0, 0);
            ii = __builtin_amdgcn_mfma_f32_16x16x32_bf16(xr, Wi[nb][t], ii, 0, 0, 0);
            const int hcol = n * 512 + (t * 16 + lrow);
#pragma unroll
            for (int r = 0; r < 4; ++r) {
                const int d = lgrp * 4 + r;
                H[hcol + d * 32]        = f2bf(fmaxf(rr[r] + b1r_[nb][t], 0.f));
                H[4096 + hcol + d * 32] = f2bf(fmaxf(ii[r] + b1i_[nb][t], 0.f));
            }
        }
    }
    __syncthreads();

#pragma unroll
    for (int nb = 0; nb < 2; ++nb) {
        const int n = 2 * wv + nb;
#pragma unroll
        for (int t = 0; t < 2; ++t) {
            const int col = t * 16 + lrow;
#pragma unroll
            for (int j = 0; j < 8; ++j) {
                const int k = lgrp * 8 + j;
                Wr[nb][t][j] = (short)f2bf(w2[n * 1024 + k * 32 + col]);
                Wi[nb][t][j] = (short)f2bf(w2[8192 + n * 1024 + k * 32 + col]);
            }
        }
    }

    f32x4 arr[2][2], aii[2][2];
#pragma unroll
    for (int nb = 0; nb < 2; ++nb) {
        const int n = 2 * wv + nb;
        const int hbase = 16384 + n * 1024 + lrow * 64 + lgrp * 16;
        bf16x8 hr  = *(const bf16x8*)(smem + hbase);
        bf16x8 hi  = *(const bf16x8*)(smem + 8192 + hbase);
        bf16x8 nhi = bneg(hi);
#pragma unroll
        for (int t = 0; t < 2; ++t) {
            f32x4 rr = __builtin_amdgcn_mfma_f32_16x16x32_bf16(hr, Wr[nb][t], zero, 0, 0, 0);
            rr = __builtin_amdgcn_mfma_f32_16x16x32_bf16(nhi, Wi[nb][t], rr, 0, 0, 0);
            f32x4 ii = __builtin_amdgcn_mfma_f32_16x16x32_bf16(hi, Wr[nb][t], zero, 0, 0, 0);
            ii = __builtin_amdgcn_mfma_f32_16x16x32_bf16(hr, Wi[nb][t], ii, 0, 0, 0);
            arr[nb][t] = rr;  aii[nb][t] = ii;
        }
    }
    __syncthreads();

    float2* FO = (float2*)smem;
#pragma unroll
    for (int nb = 0; nb < 2; ++nb) {
        const int n = 2 * wv + nb;
#pragma unroll
        for (int t = 0; t < 2; ++t) {
            const int co = n * 32 + t * 16 + lrow;
#pragma unroll
            for (int r = 0; r < 4; ++r) {
                const int d = lgrp * 4 + r;
                FO[d * 256 + co] = make_float2(softshrink(arr[nb][t][r] + b2r_[nb][t]),
                                               softshrink(aii[nb][t][r] + b2i_[nb][t]));
            }
        }
    }
    __syncthreads();

#pragma unroll
    for (int d = 0; d < DD; ++d) v[d] = FO[d * 256 + c];
    cfft<16, true>(v);
#pragma unroll
    for (int d = 0; d < DD; ++d) ps[(size_t)d * sd] = v[d];
}

// Kernel E: irfft along W via Hermitian pack + complex iFFT-32 + bias add.
// Load-pair-then-pack (inputs die immediately); __launch_bounds__(256,1) tells
// the allocator to optimize for 1 wave/EU -> no occupancy-driven spilling.
// Imag of DC/Nyquist dropped (matches numpy c2r semantics). grid (H, D, B).
__global__ __launch_bounds__(256, 1) void kE(const float2* __restrict__ spec, const float* __restrict__ x,
                                             float* __restrict__ out) {
    const int h = blockIdx.x, d = blockIdx.y, b = blockIdx.z, c = threadIdx.x;
    const float2* ps = spec + (((size_t)(b * DD + d) * HH + h) * WF) * CC + c;
    float2 v[32];
    {
        float a0 = ps[0].x;                       // Im(DC) dropped
        float r32 = ps[(size_t)32 * CC].x;        // Nyquist: real part only
        v[0] = make_float2(a0 + r32, a0 - r32);
    }
    {
        float2 a = ps[(size_t)16 * CC];
        v[16] = make_float2(2.0f * a.x, -2.0f * a.y);
    }
#pragma unroll
    for (int k = 1; k < 16; ++k) {
        const int m = 32 - k;
        float2 a  = ps[(size_t)k * CC];
        float2 bb = ps[(size_t)m * CC];
        float th = 3.14159265358979323846f * (float)k / 32.0f;
        float ss, cc;
        __sincosf(th, &ss, &cc);
        // Z[k]
        float2 E = make_float2(a.x + bb.x, a.y - bb.y);
        float2 D = make_float2(a.x - bb.x, a.y + bb.y);
        float2 O = make_float2(D.x * cc - D.y * ss, D.x * ss + D.y * cc);   // D * (cc, ss)
        v[k] = make_float2(E.x - O.y, E.y + O.x);
        // Z[32-k]: t = (-cc, ss)
        float2 Em = make_float2(bb.x + a.x, bb.y - a.y);
        float2 Dm = make_float2(bb.x - a.x, bb.y + a.y);
        float2 Om = make_float2(Dm.x * (-cc) - Dm.y * ss, Dm.x * ss + Dm.y * (-cc));
        v[m] = make_float2(Em.x - Om.y, Em.y + Om.x);
    }
    cfft<32, true>(v);

    const size_t xb = (((size_t)(b * DD + d) * HH + h) * WW) * CC + c;
    const float s = 1.0f / 256.0f;
#pragma unroll
    for (int m = 0; m < 32; ++m) {
        out[xb + (size_t)(2 * m) * CC]     = v[m].x * s + x[xb + (size_t)(2 * m) * CC];
        out[xb + (size_t)(2 * m + 1) * CC] = v[m].y * s + x[xb + (size_t)(2 * m + 1) * CC];
    }
}

extern "C" void kernel_launch(void* const* d_in, const int* in_sizes, int n_in,
                              void* d_out, int out_size, void* d_ws, size_t ws_size,
                              hipStream_t stream) {
    const float* x  = (const float*)d_in[0];
    const float* w1 = (const float*)d_in[1];
    const float* b1 = (const float*)d_in[2];
    const float* w2 = (const float*)d_in[3];
    const float* b2 = (const float*)d_in[4];
    float* out = (float*)d_out;
    float2* spec = (float2*)d_ws;  // [B][D][H][WF][C] complex, 138,412,032 bytes

    dim3 blk(256);
    kA<<<dim3(HH, DD, BB), blk, 0, stream>>>(x, spec);
    kH<false><<<dim3(WF, DD, BB), blk, 0, stream>>>(spec);
    kC<<<dim3(WF, HH, BB), blk, 0, stream>>>(spec, w1, b1, w2, b2);
    kH<true><<<dim3(WF, DD, BB), blk, 0, stream>>>(spec);
    kE<<<dim3(HH, DD, BB), blk, 0, stream>>>(spec, x, out);
}

// Round 7
// 276.079 us; speedup vs baseline: 1.1522x; 1.1522x over previous
//
#include <hip/hip_runtime.h>
#include <math.h>

#define BB 2
#define DD 16
#define HH 64
#define WW 64
#define WF 33   // WW/2+1
#define CC 256

typedef __attribute__((ext_vector_type(8))) short bf16x8;
typedef __attribute__((ext_vector_type(4))) float f32x4;
typedef __attribute__((ext_vector_type(4))) unsigned int u32x4;

__device__ __forceinline__ unsigned short f2bf(float f) {
    unsigned u = __builtin_bit_cast(unsigned int, f);
    u += 0x7fffu + ((u >> 16) & 1u);   // round-to-nearest-even
    return (unsigned short)(u >> 16);
}

__device__ __forceinline__ bf16x8 bneg(bf16x8 a) {
    u32x4 u = __builtin_bit_cast(u32x4, a);
    u = u ^ 0x80008000u;               // flip both packed bf16 signs
    return __builtin_bit_cast(bf16x8, u);
}

__device__ __forceinline__ float2 cmul(float2 a, float2 b) {
    return make_float2(a.x * b.x - a.y * b.y, a.x * b.y + a.y * b.x);
}

// Fully-unrolled in-register radix-2 DIT complex FFT. INV=true => e^{+i}, unnormalized.
template <int N, bool INV>
__device__ __forceinline__ void cfft(float2* v) {
    constexpr int L = (N == 64) ? 6 : (N == 32) ? 5 : (N == 16) ? 4 : 0;
    static_assert(L > 0, "unsupported N");
#pragma unroll
    for (int i = 0; i < N; ++i) {
        int j = 0;
#pragma unroll
        for (int bpos = 0; bpos < L; ++bpos) j |= ((i >> bpos) & 1) << (L - 1 - bpos);
        if (j > i) { float2 t = v[i]; v[i] = v[j]; v[j] = t; }
    }
#pragma unroll
    for (int s = 1; s <= L; ++s) {
        const int m = 1 << s;
#pragma unroll
        for (int k = 0; k < N; k += m) {
#pragma unroll
            for (int j = 0; j < m / 2; ++j) {
                float ang = (INV ? 2.0f : -2.0f) * 3.14159265358979323846f * (float)j / (float)m;
                float ss, cc;
                __sincosf(ang, &ss, &cc);
                float2 w = make_float2(cc, ss);
                float2 u = v[k + j];
                float2 t = cmul(w, v[k + j + m / 2]);
                v[k + j]         = make_float2(u.x + t.x, u.y + t.y);
                v[k + j + m / 2] = make_float2(u.x - t.x, u.y - t.y);
            }
        }
    }
}

// Kernel A: rfft along W via packed complex FFT-32 + Hermitian unpack.
// grid (H, D, B), 256 threads = channels.
__global__ __launch_bounds__(256) void kA(const float* __restrict__ x, float2* __restrict__ spec) {
    const int h = blockIdx.x, d = blockIdx.y, b = blockIdx.z, c = threadIdx.x;
    const float* px = x + (((size_t)(b * DD + d) * HH + h) * WW) * CC + c;
    float2 z[32];
#pragma unroll
    for (int m = 0; m < 32; ++m)
        z[m] = make_float2(px[(size_t)(2 * m) * CC], px[(size_t)(2 * m + 1) * CC]);
    cfft<32, false>(z);
    float2* ps = spec + (((size_t)(b * DD + d) * HH + h) * WF) * CC + c;
    const float s = 1.0f / 256.0f;
    // k=0 / k=32 (Nyquist): X0 = ReZ0 + ImZ0, X32 = ReZ0 - ImZ0 (both real)
    ps[0]                 = make_float2((z[0].x + z[0].y) * s, 0.0f);
    ps[(size_t)32 * CC]   = make_float2((z[0].x - z[0].y) * s, 0.0f);
#pragma unroll
    for (int k = 1; k < 32; ++k) {
        float2 a = z[k], bb = z[32 - k];
        float2 E = make_float2(0.5f * (a.x + bb.x), 0.5f * (a.y - bb.y));
        float2 P = make_float2(0.5f * (a.x - bb.x), 0.5f * (a.y + bb.y));
        float th = 3.14159265358979323846f * (float)k / 32.0f;
        float ss, cc;
        __sincosf(th, &ss, &cc);
        float2 u = make_float2(-ss, -cc);        // e^{-i th} * (-i)
        float2 X = make_float2(E.x + u.x * P.x - u.y * P.y,
                               E.y + u.x * P.y + u.y * P.x);
        ps[(size_t)k * CC] = make_float2(X.x * s, X.y * s);
    }
}

// Kernel B/D: complex FFT along H, in-place. grid (WF, D, B).
template <bool INV>
__global__ __launch_bounds__(256) void kH(float2* __restrict__ spec) {
    const int wf = blockIdx.x, d = blockIdx.y, b = blockIdx.z, c = threadIdx.x;
    float2* ps = spec + (((size_t)(b * DD + d) * HH) * WF + wf) * CC + c;
    const size_t sh = (size_t)WF * CC;
    float2 v[HH];
#pragma unroll
    for (int h = 0; h < HH; ++h) v[h] = ps[(size_t)h * sh];
    cfft<64, INV>(v);
#pragma unroll
    for (int h = 0; h < HH; ++h) ps[(size_t)h * sh] = v[h];
}

__device__ __forceinline__ float softshrink(float v) {
    return (v > 0.01f) ? v - 0.01f : ((v < -0.01f) ? v + 0.01f : 0.0f);
}

// Kernel C: FFT-D + MFMA block-MLP + iFFT-D, in-place. grid (WF, H, B), 256 thr = 4 waves.
__global__ __launch_bounds__(256) void kC(float2* __restrict__ spec,
                                          const float* __restrict__ w1, const float* __restrict__ b1,
                                          const float* __restrict__ w2, const float* __restrict__ b2) {
    const int wf = blockIdx.x, h = blockIdx.y, b = blockIdx.z;
    const int c = threadIdx.x;
    const int wv = c >> 6, lane = c & 63;
    const int lrow = lane & 15, lgrp = lane >> 4;

    __shared__ __align__(16) unsigned char smem[32768];

    float2* ps = spec + (((size_t)b * DD * HH + h) * WF + wf) * CC + c;
    const size_t sd = (size_t)HH * WF * CC;

    float b1r_[2][2], b1i_[2][2], b2r_[2][2], b2i_[2][2];
#pragma unroll
    for (int nb = 0; nb < 2; ++nb) {
        const int n = 2 * wv + nb;
#pragma unroll
        for (int t = 0; t < 2; ++t) {
            const int ob = n * 32 + t * 16 + lrow;
            b1r_[nb][t] = b1[ob];  b1i_[nb][t] = b1[256 + ob];
            b2r_[nb][t] = b2[ob];  b2i_[nb][t] = b2[256 + ob];
        }
    }

    bf16x8 Wr[2][2], Wi[2][2];
#pragma unroll
    for (int nb = 0; nb < 2; ++nb) {
        const int n = 2 * wv + nb;
#pragma unroll
        for (int t = 0; t < 2; ++t) {
            const int col = t * 16 + lrow;
#pragma unroll
            for (int j = 0; j < 8; ++j) {
                const int k = lgrp * 8 + j;
                Wr[nb][t][j] = (short)f2bf(w1[n * 1024 + k * 32 + col]);
                Wi[nb][t][j] = (short)f2bf(w1[8192 + n * 1024 + k * 32 + col]);
            }
        }
    }

    float2 v[DD];
#pragma unroll
    for (int d = 0; d < DD; ++d) v[d] = ps[(size_t)d * sd];
    cfft<16, false>(v);

    {
        const int n = c >> 5, in = c & 31;
        unsigned short* Ar = (unsigned short*)smem;
#pragma unroll
        for (int d = 0; d < DD; ++d) {
            Ar[n * 512 + d * 32 + in]        = f2bf(v[d].x);
            Ar[4096 + n * 512 + d * 32 + in] = f2bf(v[d].y);
        }
    }
    __syncthreads();

    const f32x4 zero = {0.f, 0.f, 0.f, 0.f};

#pragma unroll
    for (int nb = 0; nb < 2; ++nb) {
        const int n = 2 * wv + nb;
        const int abase = n * 1024 + lrow * 64 + lgrp * 16;
        bf16x8 xr  = *(const bf16x8*)(smem + abase);
        bf16x8 xi  = *(const bf16x8*)(smem + 8192 + abase);
        bf16x8 nxi = bneg(xi);
        unsigned short* H = (unsigned short*)(smem + 16384);
#pragma unroll
        for (int t = 0; t < 2; ++t) {
            f32x4 rr = __builtin_amdgcn_mfma_f32_16x16x32_bf16(xr, Wr[nb][t], zero, 0, 0, 0);
            rr = __builtin_amdgcn_mfma_f32_16x16x32_bf16(nxi, Wi[nb][t], rr, 0, 0, 0);
            f32x4 ii = __builtin_amdgcn_mfma_f32_16x16x32_bf16(xi, Wr[nb][t], zero, 0, 0, 0);
            ii = __builtin_amdgcn_mfma_f32_16x16x32_bf16(xr, Wi[nb][t], ii, 0, 0, 0);
            const int hcol = n * 512 + (t * 16 + lrow);
#pragma unroll
            for (int r = 0; r < 4; ++r) {
                const int d = lgrp * 4 + r;
                H[hcol + d * 32]        = f2bf(fmaxf(rr[r] + b1r_[nb][t], 0.f));
                H[4096 + hcol + d * 32] = f2bf(fmaxf(ii[r] + b1i_[nb][t], 0.f));
            }
        }
    }
    __syncthreads();

#pragma unroll
    for (int nb = 0; nb < 2; ++nb) {
        const int n = 2 * wv + nb;
#pragma unroll
        for (int t = 0; t < 2; ++t) {
            const int col = t * 16 + lrow;
#pragma unroll
            for (int j = 0; j < 8; ++j) {
                const int k = lgrp * 8 + j;
                Wr[nb][t][j] = (short)f2bf(w2[n * 1024 + k * 32 + col]);
                Wi[nb][t][j] = (short)f2bf(w2[8192 + n * 1024 + k * 32 + col]);
            }
        }
    }

    f32x4 arr[2][2], aii[2][2];
#pragma unroll
    for (int nb = 0; nb < 2; ++nb) {
        const int n = 2 * wv + nb;
        const int hbase = 16384 + n * 1024 + lrow * 64 + lgrp * 16;
        bf16x8 hr  = *(const bf16x8*)(smem + hbase);
        bf16x8 hi  = *(const bf16x8*)(smem + 8192 + hbase);
        bf16x8 nhi = bneg(hi);
#pragma unroll
        for (int t = 0; t < 2; ++t) {
            f32x4 rr = __builtin_amdgcn_mfma_f32_16x16x32_bf16(hr, Wr[nb][t], zero, 0, 0, 0);
            rr = __builtin_amdgcn_mfma_f32_16x16x32_bf16(nhi, Wi[nb][t], rr, 0, 0, 0);
            f32x4 ii = __builtin_amdgcn_mfma_f32_16x16x32_bf16(hi, Wr[nb][t], zero, 0, 0, 0);
            ii = __builtin_amdgcn_mfma_f32_16x16x32_bf16(hr, Wi[nb][t], ii, 0, 0, 0);
            arr[nb][t] = rr;  aii[nb][t] = ii;
        }
    }
    __syncthreads();

    float2* FO = (float2*)smem;
#pragma unroll
    for (int nb = 0; nb < 2; ++nb) {
        const int n = 2 * wv + nb;
#pragma unroll
        for (int t = 0; t < 2; ++t) {
            const int co = n * 32 + t * 16 + lrow;
#pragma unroll
            for (int r = 0; r < 4; ++r) {
                const int d = lgrp * 4 + r;
                FO[d * 256 + co] = make_float2(softshrink(arr[nb][t][r] + b2r_[nb][t]),
                                               softshrink(aii[nb][t][r] + b2i_[nb][t]));
            }
        }
    }
    __syncthreads();

#pragma unroll
    for (int d = 0; d < DD; ++d) v[d] = FO[d * 256 + c];
    cfft<16, true>(v);
#pragma unroll
    for (int d = 0; d < DD; ++d) ps[(size_t)d * sd] = v[d];
}

// Kernel E (r3 form, known-good codegen): Hermitian-extend + full inverse
// FFT-64 along W + ortho scale + bias. Real part of the length-64 iFFT is
// exactly numpy's irfft (Im(DC)/Im(Nyq) only affect the discarded imag).
// grid (H, D, B).
__global__ __launch_bounds__(256) void kE(const float2* __restrict__ spec, const float* __restrict__ x,
                                          float* __restrict__ out) {
    const int h = blockIdx.x, d = blockIdx.y, b = blockIdx.z, c = threadIdx.x;
    const float2* ps = spec + (((size_t)(b * DD + d) * HH + h) * WF) * CC + c;
    float2 v[WW];
#pragma unroll
    for (int k = 0; k < WF; ++k) v[k] = ps[(size_t)k * CC];
#pragma unroll
    for (int k = WF; k < WW; ++k) { float2 t = v[WW - k]; v[k] = make_float2(t.x, -t.y); }
    cfft<64, true>(v);
    const size_t xb = (((size_t)(b * DD + d) * HH + h) * WW) * CC + c;
#pragma unroll
    for (int w = 0; w < WW; ++w) {
        out[xb + (size_t)w * CC] = v[w].x * (1.0f / 256.0f) + x[xb + (size_t)w * CC];
    }
}

extern "C" void kernel_launch(void* const* d_in, const int* in_sizes, int n_in,
                              void* d_out, int out_size, void* d_ws, size_t ws_size,
                              hipStream_t stream) {
    const float* x  = (const float*)d_in[0];
    const float* w1 = (const float*)d_in[1];
    const float* b1 = (const float*)d_in[2];
    const float* w2 = (const float*)d_in[3];
    const float* b2 = (const float*)d_in[4];
    float* out = (float*)d_out;
    float2* spec = (float2*)d_ws;  // [B][D][H][WF][C] complex, 138,412,032 bytes

    dim3 blk(256);
    kA<<<dim3(HH, DD, BB), blk, 0, stream>>>(x, spec);
    kH<false><<<dim3(WF, DD, BB), blk, 0, stream>>>(spec);
    kC<<<dim3(WF, HH, BB), blk, 0, stream>>>(spec, w1, b1, w2, b2);
    kH<true><<<dim3(WF, DD, BB), blk, 0, stream>>>(spec);
    kE<<<dim3(HH, DD, BB), blk, 0, stream>>>(spec, x, out);
}